// Round 1
// baseline (42672.940 us; speedup 1.0000x reference)
//
#include <hip/hip_runtime.h>

typedef unsigned short u16;
typedef __attribute__((ext_vector_type(8))) short bh8;
typedef __attribute__((ext_vector_type(4))) short sh4;
typedef __attribute__((ext_vector_type(4))) float f4;

#define GRID_BLOCKS 512
#define THREADS 256
// XOR swizzle within a 64-u16 row (row stride 128 B): spreads 16-row column
// reads across 8 distinct 16-B slots -> ds_read_b128 at the bank floor.
#define SWZ(r, c) ((((r) * 64 + (c))) ^ ((((r) & 7)) << 3))

__device__ __forceinline__ u16 f2b(float f) {
  unsigned u = __float_as_uint(f);
  return (u16)((u + 0x7FFFu + ((u >> 16) & 1u)) >> 16);
}
__device__ __forceinline__ float elu_f(float x) { return x > 0.f ? x : __expf(x) - 1.f; }
__device__ __forceinline__ float sigm_f(float x) { return 1.f / (1.f + __expf(-x)); }
__device__ __forceinline__ float softplus_f(float x) { return x > 20.f ? x : log1pf(__expf(x)); }

// Device-scope software grid barrier (monotonic counter; bar zeroed by
// hipMemsetAsync before launch). grid(512) == exact co-residency:
// __launch_bounds__(256,2) -> 2 blocks/CU * 256 CUs = 512.
__device__ __forceinline__ void gbar(int* bar, int target) {
  __syncthreads();
  if (threadIdx.x == 0) {
    __threadfence();
    __hip_atomic_fetch_add(bar, 1, __ATOMIC_RELEASE, __HIP_MEMORY_SCOPE_AGENT);
    while (__hip_atomic_load(bar, __ATOMIC_ACQUIRE, __HIP_MEMORY_SCOPE_AGENT) < target)
      __builtin_amdgcn_s_sleep(2);
    __threadfence();
  }
  __syncthreads();
}

struct RArgs {
  const float* actions; const float* nont; const float* obs; const float* noise;
  const float* init_stoc; const float* init_deter;
  const float* W_in; const float* b_in; const float* W_ih; const float* W_hh;
  const float* b_ih; const float* b_hh;
  const float* Wp1; const float* bp1; const float* Wp2; const float* bp2;
  const float* Wq1; const float* bq1; const float* Wq2; const float* bq2;
  float* out;
  u16 *Wi_b, *Wih_b, *Whh_b, *Wp1_b, *Wp2_b, *Wq1_b, *Wq2_b;
  u16 *xin, *x_b, *hprev_b, *hb, *obs_cur, *g1;
  float *h32, *gg;
  int* bar;
};

// C[64x128] = A[64xK] * B^T[128xK], bf16 in, fp32 acc.
// Double-buffered LDS + one-ahead register prefetch; swizzled LDS layout.
// 1 __syncthreads per 64-wide K slab; next slab's global loads are in
// flight during the current slab's ds_read+MFMA.
__device__ __forceinline__ void gemm_tile_64x128(
    const u16* A, long lda, const u16* Bw, long ldb, int K, int m0,
    char* sm, f4 acc[2][4])
{
  u16* const sA0 = (u16*)sm;              // 8192 B each
  u16* const sA1 = (u16*)(sm + 8192);
  u16* const sB0 = (u16*)(sm + 16384);    // 16384 B each
  u16* const sB1 = (u16*)(sm + 32768);
  const int tid = threadIdx.x;
  const int l = tid & 63, w = tid >> 6;
  const int wrow = (w & 1) * 32, wcol = (w >> 1) * 64;
  const int am = l & 15, ak = (l >> 4) * 8;
  const int arow = tid >> 2, acol = (tid & 3) * 16;
  const int brow = tid >> 1, bcol = (tid & 1) * 32;
  const f4 z4 = {0.f, 0.f, 0.f, 0.f};
#pragma unroll
  for (int i = 0; i < 2; ++i)
#pragma unroll
    for (int j = 0; j < 4; ++j) acc[i][j] = z4;

  bh8 ra0, ra1, rb0, rb1, rb2, rb3;
  const u16* asrc = A + (long)(m0 + arow) * lda + acol;
  const u16* bsrc = Bw + (long)brow * ldb + bcol;
  auto fetch = [&](int k0) {
    ra0 = *(const bh8*)(asrc + k0);
    ra1 = *(const bh8*)(asrc + k0 + 8);
    rb0 = *(const bh8*)(bsrc + k0);
    rb1 = *(const bh8*)(bsrc + k0 + 8);
    rb2 = *(const bh8*)(bsrc + k0 + 16);
    rb3 = *(const bh8*)(bsrc + k0 + 24);
  };
  auto put = [&](u16* dA, u16* dB) {
    *(bh8*)(dA + SWZ(arow, acol)) = ra0;
    *(bh8*)(dA + SWZ(arow, acol + 8)) = ra1;
    *(bh8*)(dB + SWZ(brow, bcol)) = rb0;
    *(bh8*)(dB + SWZ(brow, bcol + 8)) = rb1;
    *(bh8*)(dB + SWZ(brow, bcol + 16)) = rb2;
    *(bh8*)(dB + SWZ(brow, bcol + 24)) = rb3;
  };

  fetch(0);
  put(sA0, sB0);
  const int nIter = K >> 6;
  for (int i = 0; i < nIter; ++i) {
    __syncthreads();                       // buf (i&1) ready; prev reads done
    if (i + 1 < nIter) fetch((i + 1) << 6);  // issue next loads early
    const u16* cA = (i & 1) ? sA1 : sA0;
    const u16* cB = (i & 1) ? sB1 : sB0;
#pragma unroll
    for (int kc = 0; kc < 64; kc += 32) {
      bh8 a0 = *(const bh8*)(cA + SWZ(wrow + am, kc + ak));
      bh8 a1 = *(const bh8*)(cA + SWZ(wrow + 16 + am, kc + ak));
#pragma unroll
      for (int j = 0; j < 4; ++j) {
        bh8 bv = *(const bh8*)(cB + SWZ(wcol + j * 16 + am, kc + ak));
        acc[0][j] = __builtin_amdgcn_mfma_f32_16x16x32_bf16(a0, bv, acc[0][j], 0, 0, 0);
        acc[1][j] = __builtin_amdgcn_mfma_f32_16x16x32_bf16(a1, bv, acc[1][j], 0, 0, 0);
      }
    }
    if (i + 1 < nIter) put((i & 1) ? sA0 : sA1, (i & 1) ? sB0 : sB1);
  }
  __syncthreads();
}

__global__ __launch_bounds__(THREADS, 2) void rssm_kernel(RArgs a) {
  __shared__ __align__(16) char sm[49152];
  const int tid = threadIdx.x;
  const int bid = blockIdx.x;
  const long gsz = (long)GRID_BLOCKS * THREADS;
  const long g0 = (long)bid * THREADS + tid;
  const int l = tid & 63, w = tid >> 6;
  const int dr = (l >> 4) * 4, dc = l & 15;
  const int wrow = (w & 1) * 32, wcol = (w >> 1) * 64;
  // q1 fp32 partials aliased into gg: gg is dead between stage C (read) and
  // next step's stage B (write); q1a/q1b live stage D (write) -> E (read).
  float* const q1a = a.gg;
  float* const q1b = a.gg + (long)512 * 1024;
  int round = 0;

  // ---- init / weight conversion (every call: ws is re-poisoned) ----
  for (long i = g0; i < 3072L * 1024 / 4; i += gsz) {
    f4 v1 = *(const f4*)(a.W_ih + i * 4);
    f4 v2 = *(const f4*)(a.W_hh + i * 4);
    sh4 o1 = {(short)f2b(v1[0]), (short)f2b(v1[1]), (short)f2b(v1[2]), (short)f2b(v1[3])};
    sh4 o2 = {(short)f2b(v2[0]), (short)f2b(v2[1]), (short)f2b(v2[2]), (short)f2b(v2[3])};
    *(sh4*)(a.Wih_b + i * 4) = o1;
    *(sh4*)(a.Whh_b + i * 4) = o2;
  }
  for (long i = g0; i < 1024L * 2048 / 4; i += gsz) {
    f4 v = *(const f4*)(a.Wq1 + i * 4);
    sh4 o = {(short)f2b(v[0]), (short)f2b(v[1]), (short)f2b(v[2]), (short)f2b(v[3])};
    *(sh4*)(a.Wq1_b + i * 4) = o;
  }
  for (long i = g0; i < 1024L * 1024 / 4; i += gsz) {
    f4 v = *(const f4*)(a.Wp1 + i * 4);
    sh4 o = {(short)f2b(v[0]), (short)f2b(v[1]), (short)f2b(v[2]), (short)f2b(v[3])};
    *(sh4*)(a.Wp1_b + i * 4) = o;
  }
  for (long i = g0; i < 256L * 1024 / 4; i += gsz) {
    f4 v = *(const f4*)(a.Wp2 + i * 4);
    f4 u = *(const f4*)(a.Wq2 + i * 4);
    sh4 o1 = {(short)f2b(v[0]), (short)f2b(v[1]), (short)f2b(v[2]), (short)f2b(v[3])};
    sh4 o2 = {(short)f2b(u[0]), (short)f2b(u[1]), (short)f2b(u[2]), (short)f2b(u[3])};
    *(sh4*)(a.Wp2_b + i * 4) = o1;
    *(sh4*)(a.Wq2_b + i * 4) = o2;
  }
  for (long i = g0; i < 1024 * 192; i += gsz) {
    long n = i / 192, k = i - n * 192;
    a.Wi_b[i] = (k < 144) ? f2b(a.W_in[n * 144 + k]) : (u16)0;
  }
  for (long i = g0; i < 512L * 1024 / 4; i += gsz)
    *(f4*)(a.h32 + i * 4) = *(const f4*)(a.init_deter + i * 4);
  for (long i = g0; i < 512 * 192; i += gsz) {
    long b = i / 192, k = i - b * 192;
    float v = 0.f;
    if (k < 128) v = a.init_stoc[b * 128 + k] * a.nont[b];
    else if (k < 144) v = a.actions[b * 16 + (k - 128)];
    a.xin[i] = f2b(v);
  }
  round += GRID_BLOCKS; gbar(a.bar, round);

  for (int t = 0; t < 64; ++t) {
    // ---- Stage A: x = elu([stoc*nt ; a] @ W_in^T + b_in)  + side converts ----
    if (bid < 64) {
      const int m0 = (bid >> 3) * 64, n0 = (bid & 7) * 128;
      f4 acc[2][4];
      gemm_tile_64x128(a.xin, 192, a.Wi_b + (long)n0 * 192, 192, 192, m0, sm, acc);
#pragma unroll
      for (int i = 0; i < 2; ++i)
#pragma unroll
        for (int j = 0; j < 4; ++j)
#pragma unroll
          for (int r = 0; r < 4; ++r) {
            int row = m0 + wrow + i * 16 + dr + r;
            int col = n0 + wcol + j * 16 + dc;
            a.x_b[(long)row * 1024 + col] = f2b(elu_f(acc[i][j][r] + a.b_in[col]));
          }
    } else if (bid < 192) {
      const int base = (bid - 64) * 4096;
      for (int i = tid; i < 1024; i += THREADS) {
        int idx = base + i * 4;
        int b = idx >> 10;
        float nt = a.nont[t * 512 + b];
        f4 v = *(const f4*)(a.h32 + idx);
        sh4 o = {(short)f2b(v[0] * nt), (short)f2b(v[1] * nt),
                 (short)f2b(v[2] * nt), (short)f2b(v[3] * nt)};
        *(sh4*)(a.hprev_b + idx) = o;
      }
    } else if (bid < 320) {
      const int base = (bid - 192) * 4096;
      const float* op = a.obs + (long)t * 512 * 1024;
      for (int i = tid; i < 1024; i += THREADS) {
        int idx = base + i * 4;
        f4 v = *(const f4*)(op + idx);
        sh4 o = {(short)f2b(v[0]), (short)f2b(v[1]), (short)f2b(v[2]), (short)f2b(v[3])};
        *(sh4*)(a.obs_cur + idx) = o;
      }
    }
    round += GRID_BLOCKS; gbar(a.bar, round);

    // ---- Stage B: gi = x @ W_ih^T ; gh = (h_prev*nt) @ W_hh^T  (raw, fp32) ----
    if (bid < 384) {
      const int tm = bid / 48, tn = bid - tm * 48;
      const int m0 = tm * 64; const long n0 = (long)tn * 128;
      const u16* Aq; const u16* Bq;
      if (n0 < 3072) { Aq = a.x_b;     Bq = a.Wih_b + n0 * 1024; }
      else           { Aq = a.hprev_b; Bq = a.Whh_b + (n0 - 3072) * 1024; }
      f4 acc[2][4];
      gemm_tile_64x128(Aq, 1024, Bq, 1024, 1024, m0, sm, acc);
#pragma unroll
      for (int i = 0; i < 2; ++i)
#pragma unroll
        for (int j = 0; j < 4; ++j)
#pragma unroll
          for (int r = 0; r < 4; ++r) {
            int row = m0 + wrow + i * 16 + dr + r;
            long col = n0 + wcol + j * 16 + dc;
            a.gg[(long)row * 6144 + col] = acc[i][j][r];
          }
    }
    round += GRID_BLOCKS; gbar(a.bar, round);

    // ---- Stage C: GRU combine (elementwise, fp32 state, f4-vectorized) ----
    for (long i4 = g0; i4 < 512L * 1024 / 4; i4 += gsz) {
      const int b = (int)(i4 >> 8);
      const int c = (int)(i4 & 255) * 4;
      const float* g = a.gg + (long)b * 6144;
      const float nt = a.nont[t * 512 + b];
      f4 gir = *(const f4*)(g + c);
      f4 giz = *(const f4*)(g + 1024 + c);
      f4 gin = *(const f4*)(g + 2048 + c);
      f4 ghr = *(const f4*)(g + 3072 + c);
      f4 ghz = *(const f4*)(g + 4096 + c);
      f4 ghn = *(const f4*)(g + 5120 + c);
      f4 bir = *(const f4*)(a.b_ih + c);
      f4 biz = *(const f4*)(a.b_ih + 1024 + c);
      f4 bin = *(const f4*)(a.b_ih + 2048 + c);
      f4 bhr = *(const f4*)(a.b_hh + c);
      f4 bhz = *(const f4*)(a.b_hh + 1024 + c);
      f4 bhn = *(const f4*)(a.b_hh + 2048 + c);
      f4 hp = *(const f4*)(a.h32 + (long)b * 1024 + c);
      f4 h4; sh4 hb4;
#pragma unroll
      for (int j = 0; j < 4; ++j) {
        float r = sigm_f(gir[j] + bir[j] + ghr[j] + bhr[j]);
        float z = sigm_f(giz[j] + biz[j] + ghz[j] + bhz[j]);
        float n = tanhf(gin[j] + bin[j] + r * (ghn[j] + bhn[j]));
        float hpv = hp[j] * nt;
        float h = (1.f - z) * n + z * hpv;
        h4[j] = h; hb4[j] = (short)f2b(h);
      }
      *(f4*)(a.h32 + (long)b * 1024 + c) = h4;
      *(sh4*)(a.hb + (long)b * 1024 + c) = hb4;
      *(f4*)(a.out + ((long)t * 512 + b) * 1536 + 512 + c) = h4;
    }
    round += GRID_BLOCKS; gbar(a.bar, round);

    // ---- Stage D: p1 = elu(h@Wp1^T+bp1) bf16; q1 split-K: raw fp32 partials
    //      q1a = h@Wq1[:, :1024]^T ; q1b = obs@Wq1[:, 1024:]^T (combined in E) ----
    if (bid < 192) {
      f4 acc[2][4];
      const int u = bid & 63;
      const int m0 = (u >> 3) * 64, n0 = (u & 7) * 128;
      if (bid < 64) {
        gemm_tile_64x128(a.hb, 1024, a.Wp1_b + (long)n0 * 1024, 1024, 1024, m0, sm, acc);
#pragma unroll
        for (int i = 0; i < 2; ++i)
#pragma unroll
          for (int j = 0; j < 4; ++j)
#pragma unroll
            for (int r = 0; r < 4; ++r) {
              int row = m0 + wrow + i * 16 + dr + r;
              int col = n0 + wcol + j * 16 + dc;
              a.g1[(long)row * 1024 + col] = f2b(elu_f(acc[i][j][r] + a.bp1[col]));
            }
      } else if (bid < 128) {
        gemm_tile_64x128(a.hb, 1024, a.Wq1_b + (long)n0 * 2048, 2048, 1024, m0, sm, acc);
#pragma unroll
        for (int i = 0; i < 2; ++i)
#pragma unroll
          for (int j = 0; j < 4; ++j)
#pragma unroll
            for (int r = 0; r < 4; ++r) {
              int row = m0 + wrow + i * 16 + dr + r;
              int col = n0 + wcol + j * 16 + dc;
              q1a[(long)row * 1024 + col] = acc[i][j][r];
            }
      } else {
        gemm_tile_64x128(a.obs_cur, 1024, a.Wq1_b + (long)n0 * 2048 + 1024, 2048, 1024, m0, sm, acc);
#pragma unroll
        for (int i = 0; i < 2; ++i)
#pragma unroll
          for (int j = 0; j < 4; ++j)
#pragma unroll
            for (int r = 0; r < 4; ++r) {
              int row = m0 + wrow + i * 16 + dr + r;
              int col = n0 + wcol + j * 16 + dc;
              q1b[(long)row * 1024 + col] = acc[i][j][r];
            }
      }
    }
    round += GRID_BLOCKS; gbar(a.bar, round);

    // ---- Stage E: p2/q2 (16x256 tiles, K=1024) + sample + outputs + next xin ----
    if (bid < 64) {
      const bool isQ = bid >= 32;
      const int m0 = (bid & 31) * 16;
      const u16* Bq = isQ ? a.Wq2_b : a.Wp2_b;
      const float* bias = isQ ? a.bq2 : a.bp2;
      u16* const sA = (u16*)sm;            // [16][64] swizzled
      u16* const sB = (u16*)(sm + 2048);   // [256][64] swizzled
      const f4 z4 = {0.f, 0.f, 0.f, 0.f};
      f4 acc[4];
#pragma unroll
      for (int j = 0; j < 4; ++j) acc[j] = z4;
      const int am = l & 15, ak = (l >> 4) * 8;
      const int f = tid * 4;
      const int ar = f >> 6, ac = f & 63;
      const int br_ = tid >> 3, bc_ = (tid & 7) * 8;
      f4 va, vb; unsigned long long rA; bh8 rB[8];
      auto fetchE = [&](int k0) {
        if (isQ) {
          long base = (long)(m0 + ar) * 1024 + k0 + ac;
          va = *(const f4*)(q1a + base);
          vb = *(const f4*)(q1b + base);
        } else {
          rA = *(const unsigned long long*)(a.g1 + (long)(m0 + ar) * 1024 + k0 + ac);
        }
#pragma unroll
        for (int i = 0; i < 8; ++i)
          rB[i] = *(const bh8*)(Bq + (long)(i * 32 + br_) * 1024 + k0 + bc_);
      };
      auto putE = [&](int k0) {
        if (isQ) {
          f4 bi = *(const f4*)(a.bq1 + k0 + ac);
          union { unsigned long long u; u16 s[4]; } pk;
#pragma unroll
          for (int j = 0; j < 4; ++j) pk.s[j] = f2b(elu_f(va[j] + vb[j] + bi[j]));
          *(unsigned long long*)(sA + SWZ(ar, ac)) = pk.u;
        } else {
          *(unsigned long long*)(sA + SWZ(ar, ac)) = rA;
        }
#pragma unroll
        for (int i = 0; i < 8; ++i)
          *(bh8*)(sB + SWZ(i * 32 + br_, bc_)) = rB[i];
      };
      fetchE(0);
      for (int k0 = 0; k0 < 1024; k0 += 64) {
        __syncthreads();
        putE(k0);
        __syncthreads();
        if (k0 + 64 < 1024) fetchE(k0 + 64);  // next loads hidden under MFMAs
#pragma unroll
        for (int kc = 0; kc < 64; kc += 32) {
          bh8 av = *(const bh8*)(sA + SWZ(am, kc + ak));
#pragma unroll
          for (int j = 0; j < 4; ++j) {
            bh8 bv = *(const bh8*)(sB + SWZ(w * 64 + j * 16 + am, kc + ak));
            acc[j] = __builtin_amdgcn_mfma_f32_16x16x32_bf16(av, bv, acc[j], 0, 0, 0);
          }
        }
      }
      __syncthreads();
      float* sq = (float*)sm;  // [16][256], reuses dead staging LDS
      const long ob = (long)t * 512 * 1536;
#pragma unroll
      for (int j = 0; j < 4; ++j)
#pragma unroll
        for (int r = 0; r < 4; ++r) {
          int row = dr + r;
          int col = w * 64 + j * 16 + dc;
          int b = m0 + row;
          float v = acc[j][r] + bias[col];
          float o = (col < 128) ? v : (softplus_f(v) + 0.1f);
          a.out[ob + (long)b * 1536 + (isQ ? 256 : 0) + col] = o;
          if (isQ) sq[row * 256 + col] = o;
        }
      if (isQ && t + 1 < 64) {
        __syncthreads();
        for (int it = tid; it < 2048; it += THREADS) {
          int row = it >> 7, j = it & 127, b = m0 + row;
          float stoc = sq[row * 256 + j] + sq[row * 256 + 128 + j] * a.noise[((long)t * 512 + b) * 128 + j];
          a.xin[(long)b * 192 + j] = f2b(stoc * a.nont[(t + 1) * 512 + b]);
        }
        {
          int row = tid >> 4, ja = tid & 15, b = m0 + row;
          a.xin[(long)b * 192 + 128 + ja] = f2b(a.actions[((long)(t + 1) * 512 + b) * 16 + ja]);
        }
      }
    }
    round += GRID_BLOCKS; gbar(a.bar, round);
  }
}

extern "C" void kernel_launch(void* const* d_in, const int* in_sizes, int n_in,
                              void* d_out, int out_size, void* d_ws, size_t ws_size,
                              hipStream_t stream) {
  RArgs a;
  a.actions    = (const float*)d_in[0];
  a.nont       = (const float*)d_in[1];
  a.obs        = (const float*)d_in[2];
  a.noise      = (const float*)d_in[3];
  a.init_stoc  = (const float*)d_in[4];
  a.init_deter = (const float*)d_in[5];
  a.W_in = (const float*)d_in[6];  a.b_in = (const float*)d_in[7];
  a.W_ih = (const float*)d_in[8];  a.W_hh = (const float*)d_in[9];
  a.b_ih = (const float*)d_in[10]; a.b_hh = (const float*)d_in[11];
  a.Wp1 = (const float*)d_in[12];  a.bp1 = (const float*)d_in[13];
  a.Wp2 = (const float*)d_in[14];  a.bp2 = (const float*)d_in[15];
  a.Wq1 = (const float*)d_in[16];  a.bq1 = (const float*)d_in[17];
  a.Wq2 = (const float*)d_in[18];  a.bq2 = (const float*)d_in[19];
  a.out = (float*)d_out;

  char* p = (char*)d_ws;
  auto alloc = [&](size_t bytes) { char* r = p; p += (bytes + 255) & ~(size_t)255; return r; };
  a.bar     = (int*)alloc(256);
  a.Wi_b    = (u16*)alloc(1024 * 192 * 2);
  a.Wih_b   = (u16*)alloc((size_t)3072 * 1024 * 2);
  a.Whh_b   = (u16*)alloc((size_t)3072 * 1024 * 2);
  a.Wp1_b   = (u16*)alloc((size_t)1024 * 1024 * 2);
  a.Wp2_b   = (u16*)alloc((size_t)256 * 1024 * 2);
  a.Wq1_b   = (u16*)alloc((size_t)1024 * 2048 * 2);
  a.Wq2_b   = (u16*)alloc((size_t)256 * 1024 * 2);
  a.xin     = (u16*)alloc((size_t)512 * 192 * 2);
  a.x_b     = (u16*)alloc((size_t)512 * 1024 * 2);
  a.hprev_b = (u16*)alloc((size_t)512 * 1024 * 2);
  a.hb      = (u16*)alloc((size_t)512 * 1024 * 2);
  a.obs_cur = (u16*)alloc((size_t)512 * 1024 * 2);
  a.g1      = (u16*)alloc((size_t)512 * 1024 * 2);
  a.h32     = (float*)alloc((size_t)512 * 1024 * 4);
  a.gg      = (float*)alloc((size_t)512 * 6144 * 4);

  hipMemsetAsync(a.bar, 0, 256, stream);
  rssm_kernel<<<dim3(GRID_BLOCKS), dim3(THREADS), 0, stream>>>(a);
}

// Round 2
// 10784.365 us; speedup vs baseline: 3.9569x; 3.9569x over previous
//
#include <hip/hip_runtime.h>

typedef unsigned short u16;
typedef __attribute__((ext_vector_type(8))) short bh8;
typedef __attribute__((ext_vector_type(4))) short sh4;
typedef __attribute__((ext_vector_type(4))) float f4;
typedef unsigned long long u64;

#define GRID_BLOCKS 512
#define THREADS 256
// XOR swizzle at 8-element (16B) granularity within a 64-u16 row.
#define SWZ(r, c) ((((r) * 64 + (c))) ^ ((((r) & 7)) << 3))
#define SFLD 132   // f32 epilogue LDS row stride (16B-aligned, bank-spread)

__device__ __forceinline__ u16 f2b(float f) {
  unsigned u = __float_as_uint(f);
  return (u16)((u + 0x7FFFu + ((u >> 16) & 1u)) >> 16);
}
__device__ __forceinline__ float elu_f(float x) { return x > 0.f ? x : __expf(x) - 1.f; }
__device__ __forceinline__ float sigm_f(float x) { return 1.f / (1.f + __expf(-x)); }
__device__ __forceinline__ float softplus_f(float x) { return x > 20.f ? x : log1pf(__expf(x)); }

// ---- coherent (XCD-L2-bypassing) accessors for cross-block activations ----
// Relaxed agent-scope atomics compile to sc-flagged global_load/store that are
// coherent at the L3 point WITHOUT any wbl2/inv fence.
__device__ __forceinline__ u64 ldg8(const void* p) {
  return __hip_atomic_load((const u64*)p, __ATOMIC_RELAXED, __HIP_MEMORY_SCOPE_AGENT);
}
__device__ __forceinline__ void stg8(void* p, u64 v) {
  __hip_atomic_store((u64*)p, v, __ATOMIC_RELAXED, __HIP_MEMORY_SCOPE_AGENT);
}
__device__ __forceinline__ f4 ldg_f4(const float* p) {
  union { u64 q[2]; f4 v; } u;
  u.q[0] = ldg8(p); u.q[1] = ldg8(p + 2);
  return u.v;
}
__device__ __forceinline__ bh8 ldg_bh8(const u16* p) {
  union { u64 q[2]; bh8 v; } u;
  u.q[0] = ldg8(p); u.q[1] = ldg8(p + 4);
  return u.v;
}

// Full-fence barrier: ONLY for init (weights written with plain cached stores
// must be pushed to L3 once; after this they are read-only and L2-cacheable).
__device__ __forceinline__ void gbar_full(int* bar, int target) {
  __syncthreads();
  if (threadIdx.x == 0) {
    __threadfence();
    __hip_atomic_fetch_add(bar, 1, __ATOMIC_RELEASE, __HIP_MEMORY_SCOPE_AGENT);
    while (__hip_atomic_load(bar, __ATOMIC_ACQUIRE, __HIP_MEMORY_SCOPE_AGENT) < target)
      __builtin_amdgcn_s_sleep(8);
    __threadfence();
  }
  __syncthreads();
}

// Fence-free step barrier. Correctness: all cross-stage data moves via
// sc-flagged (agent-coherent) loads/stores; __syncthreads() drains each
// thread's vmcnt so flagged stores are at the coherence point before the
// counter add; consumers read flagged, so no invalidate is needed.
__device__ __forceinline__ void gbar_fast(int* bar, int target) {
  __syncthreads();
  if (threadIdx.x == 0) {
    __hip_atomic_fetch_add(bar, 1, __ATOMIC_RELAXED, __HIP_MEMORY_SCOPE_AGENT);
    while (__hip_atomic_load(bar, __ATOMIC_RELAXED, __HIP_MEMORY_SCOPE_AGENT) < target)
      __builtin_amdgcn_s_sleep(32);
  }
  __syncthreads();
}

struct RArgs {
  const float* actions; const float* nont; const float* obs; const float* noise;
  const float* init_stoc; const float* init_deter;
  const float* W_in; const float* b_in; const float* W_ih; const float* W_hh;
  const float* b_ih; const float* b_hh;
  const float* Wp1; const float* bp1; const float* Wp2; const float* bp2;
  const float* Wq1; const float* bq1; const float* Wq2; const float* bq2;
  float* out;
  u16 *Wi_b, *Wih_b, *Whh_b, *Wp1_b, *Wp2_b, *Wq1_b, *Wq2_b;
  u16 *xin, *x_b, *hprev_b, *hb, *obs_cur, *g1;
  float *h32, *gg;
  int* bar;
};

// C[64x128] = A[64xK] * B^T[128xK], bf16 in, fp32 acc.
// A = activations (flagged loads); B = weights (plain cached loads).
// Double-buffered LDS + one-ahead register prefetch; swizzled LDS layout.
__device__ __forceinline__ void gemm_tile_64x128(
    const u16* A, long lda, const u16* Bw, long ldb, int K, int m0,
    char* sm, f4 acc[2][4])
{
  u16* const sA0 = (u16*)sm;              // 8192 B each
  u16* const sA1 = (u16*)(sm + 8192);
  u16* const sB0 = (u16*)(sm + 16384);    // 16384 B each
  u16* const sB1 = (u16*)(sm + 32768);
  const int tid = threadIdx.x;
  const int l = tid & 63, w = tid >> 6;
  const int wrow = (w & 1) * 32, wcol = (w >> 1) * 64;
  const int am = l & 15, ak = (l >> 4) * 8;
  const int arow = tid >> 2, acol = (tid & 3) * 16;
  const int brow = tid >> 1, bcol = (tid & 1) * 32;
  const f4 z4 = {0.f, 0.f, 0.f, 0.f};
#pragma unroll
  for (int i = 0; i < 2; ++i)
#pragma unroll
    for (int j = 0; j < 4; ++j) acc[i][j] = z4;

  bh8 ra0, ra1, rb0, rb1, rb2, rb3;
  const u16* asrc = A + (long)(m0 + arow) * lda + acol;
  const u16* bsrc = Bw + (long)brow * ldb + bcol;
  auto fetch = [&](int k0) {
    ra0 = ldg_bh8(asrc + k0);
    ra1 = ldg_bh8(asrc + k0 + 8);
    rb0 = *(const bh8*)(bsrc + k0);
    rb1 = *(const bh8*)(bsrc + k0 + 8);
    rb2 = *(const bh8*)(bsrc + k0 + 16);
    rb3 = *(const bh8*)(bsrc + k0 + 24);
  };
  auto put = [&](u16* dA, u16* dB) {
    *(bh8*)(dA + SWZ(arow, acol)) = ra0;
    *(bh8*)(dA + SWZ(arow, acol + 8)) = ra1;
    *(bh8*)(dB + SWZ(brow, bcol)) = rb0;
    *(bh8*)(dB + SWZ(brow, bcol + 8)) = rb1;
    *(bh8*)(dB + SWZ(brow, bcol + 16)) = rb2;
    *(bh8*)(dB + SWZ(brow, bcol + 24)) = rb3;
  };

  fetch(0);
  put(sA0, sB0);
  const int nIter = K >> 6;
  for (int i = 0; i < nIter; ++i) {
    __syncthreads();                         // buf (i&1) ready; prev reads done
    if (i + 1 < nIter) fetch((i + 1) << 6);  // issue next loads early
    const u16* cA = (i & 1) ? sA1 : sA0;
    const u16* cB = (i & 1) ? sB1 : sB0;
#pragma unroll
    for (int kc = 0; kc < 64; kc += 32) {
      bh8 a0 = *(const bh8*)(cA + SWZ(wrow + am, kc + ak));
      bh8 a1 = *(const bh8*)(cA + SWZ(wrow + 16 + am, kc + ak));
#pragma unroll
      for (int j = 0; j < 4; ++j) {
        bh8 bv = *(const bh8*)(cB + SWZ(wcol + j * 16 + am, kc + ak));
        acc[0][j] = __builtin_amdgcn_mfma_f32_16x16x32_bf16(a0, bv, acc[0][j], 0, 0, 0);
        acc[1][j] = __builtin_amdgcn_mfma_f32_16x16x32_bf16(a1, bv, acc[1][j], 0, 0, 0);
      }
    }
    if (i + 1 < nIter) put((i & 1) ? sA0 : sA1, (i & 1) ? sB0 : sB1);
  }
  __syncthreads();
}

// ---- epilogues: fragment -> LDS f32 [64][SFLD] -> linear coalesced flagged
// stores (keeps cross-block stores 8B-granular and wave-contiguous) ----
__device__ __forceinline__ void frag_to_lds(float* sf, const f4 acc[2][4], int tid) {
  const int l = tid & 63, w = tid >> 6;
  const int dr = (l >> 4) * 4, dc = l & 15;
  const int wrow = (w & 1) * 32, wcol = (w >> 1) * 64;
#pragma unroll
  for (int i = 0; i < 2; ++i)
#pragma unroll
    for (int j = 0; j < 4; ++j)
#pragma unroll
      for (int r = 0; r < 4; ++r)
        sf[(wrow + i * 16 + dr + r) * SFLD + wcol + j * 16 + dc] = acc[i][j][r];
}

__device__ __forceinline__ void epi_bf16_elu(u16* dst, long ldd, int m0, long n0,
                                             const float* bias, const f4 acc[2][4],
                                             char* sm, int tid) {
  float* sf = (float*)sm;
  frag_to_lds(sf, acc, tid);
  __syncthreads();
  for (int it = tid; it < 2048; it += THREADS) {
    int row = it >> 5, c4 = (it & 31) * 4;
    f4 v = *(f4*)(sf + row * SFLD + c4);
    f4 b = *(const f4*)(bias + n0 + c4);
    union { sh4 s; u64 q; } pk;
#pragma unroll
    for (int j = 0; j < 4; ++j) pk.s[j] = (short)f2b(elu_f(v[j] + b[j]));
    stg8(dst + (long)(m0 + row) * ldd + n0 + c4, pk.q);
  }
}

__device__ __forceinline__ void epi_f32(float* dst, long ldd, int m0, long n0,
                                        const f4 acc[2][4], char* sm, int tid) {
  float* sf = (float*)sm;
  frag_to_lds(sf, acc, tid);
  __syncthreads();
  for (int it = tid; it < 2048; it += THREADS) {
    int row = it >> 5, c4 = (it & 31) * 4;
    union { f4 v; u64 q[2]; } u;
    u.v = *(f4*)(sf + row * SFLD + c4);
    float* d = dst + (long)(m0 + row) * ldd + n0 + c4;
    stg8(d, u.q[0]); stg8(d + 2, u.q[1]);
  }
}

__global__ __launch_bounds__(THREADS, 2) void rssm_kernel(RArgs a) {
  __shared__ __align__(16) char sm[49152];
  const int tid = threadIdx.x;
  const int bid = blockIdx.x;
  const long gsz = (long)GRID_BLOCKS * THREADS;
  const long g0 = (long)bid * THREADS + tid;
  const int l = tid & 63, w = tid >> 6;
  const int dr = (l >> 4) * 4, dc = l & 15;
  // q1 fp32 partials aliased into gg: gg is dead between stage C (read) and
  // next step's stage B (write); q1a/q1b live stage D (write) -> E (read).
  float* const q1a = a.gg;
  float* const q1b = a.gg + (long)512 * 1024;
  int round = 0;

  // ---- init / weight conversion (every call: ws is re-poisoned).
  // Plain cached stores; the ONE full-fence barrier below pushes them to L3.
  for (long i = g0; i < 3072L * 1024 / 4; i += gsz) {
    f4 v1 = *(const f4*)(a.W_ih + i * 4);
    f4 v2 = *(const f4*)(a.W_hh + i * 4);
    sh4 o1 = {(short)f2b(v1[0]), (short)f2b(v1[1]), (short)f2b(v1[2]), (short)f2b(v1[3])};
    sh4 o2 = {(short)f2b(v2[0]), (short)f2b(v2[1]), (short)f2b(v2[2]), (short)f2b(v2[3])};
    *(sh4*)(a.Wih_b + i * 4) = o1;
    *(sh4*)(a.Whh_b + i * 4) = o2;
  }
  for (long i = g0; i < 1024L * 2048 / 4; i += gsz) {
    f4 v = *(const f4*)(a.Wq1 + i * 4);
    sh4 o = {(short)f2b(v[0]), (short)f2b(v[1]), (short)f2b(v[2]), (short)f2b(v[3])};
    *(sh4*)(a.Wq1_b + i * 4) = o;
  }
  for (long i = g0; i < 1024L * 1024 / 4; i += gsz) {
    f4 v = *(const f4*)(a.Wp1 + i * 4);
    sh4 o = {(short)f2b(v[0]), (short)f2b(v[1]), (short)f2b(v[2]), (short)f2b(v[3])};
    *(sh4*)(a.Wp1_b + i * 4) = o;
  }
  for (long i = g0; i < 256L * 1024 / 4; i += gsz) {
    f4 v = *(const f4*)(a.Wp2 + i * 4);
    f4 u = *(const f4*)(a.Wq2 + i * 4);
    sh4 o1 = {(short)f2b(v[0]), (short)f2b(v[1]), (short)f2b(v[2]), (short)f2b(v[3])};
    sh4 o2 = {(short)f2b(u[0]), (short)f2b(u[1]), (short)f2b(u[2]), (short)f2b(u[3])};
    *(sh4*)(a.Wp2_b + i * 4) = o1;
    *(sh4*)(a.Wq2_b + i * 4) = o2;
  }
  for (long i = g0; i < 1024 * 192; i += gsz) {
    long n = i / 192, k = i - n * 192;
    a.Wi_b[i] = (k < 144) ? f2b(a.W_in[n * 144 + k]) : (u16)0;
  }
  for (long i = g0; i < 512L * 1024 / 4; i += gsz) {
    f4 v = *(const f4*)(a.init_deter + i * 4);
    *(f4*)(a.h32 + i * 4) = v;
    float nt0 = a.nont[(i * 4) >> 10];
    sh4 o = {(short)f2b(v[0] * nt0), (short)f2b(v[1] * nt0),
             (short)f2b(v[2] * nt0), (short)f2b(v[3] * nt0)};
    *(sh4*)(a.hprev_b + i * 4) = o;
  }
  for (long i = g0; i < 512L * 1024 / 4; i += gsz) {
    f4 v = *(const f4*)(a.obs + i * 4);
    sh4 o = {(short)f2b(v[0]), (short)f2b(v[1]), (short)f2b(v[2]), (short)f2b(v[3])};
    *(sh4*)(a.obs_cur + i * 4) = o;
  }
  for (long i = g0; i < 512 * 192; i += gsz) {
    long b = i / 192, k = i - b * 192;
    float v = 0.f;
    if (k < 128) v = a.init_stoc[b * 128 + k] * a.nont[b];
    else if (k < 144) v = a.actions[b * 16 + (k - 128)];
    a.xin[i] = f2b(v);
  }
  round += GRID_BLOCKS; gbar_full(a.bar, round);

  for (int t = 0; t < 64; ++t) {
    // ---- Stage A: x = elu([stoc*nt ; a] @ W_in^T + b_in) ----
    if (bid < 64) {
      const int m0 = (bid >> 3) * 64, n0 = (bid & 7) * 128;
      f4 acc[2][4];
      gemm_tile_64x128(a.xin, 192, a.Wi_b + (long)n0 * 192, 192, 192, m0, sm, acc);
      epi_bf16_elu(a.x_b, 1024, m0, n0, a.b_in, acc, sm, tid);
    }
    round += GRID_BLOCKS; gbar_fast(a.bar, round);

    // ---- Stage B: gi = x @ W_ih^T ; gh = (h_prev*nt) @ W_hh^T  (raw, fp32) ----
    if (bid < 384) {
      const int tm = bid / 48, tn = bid - tm * 48;
      const int m0 = tm * 64; const long n0 = (long)tn * 128;
      const u16* Aq; const u16* Bq;
      if (n0 < 3072) { Aq = a.x_b;     Bq = a.Wih_b + n0 * 1024; }
      else           { Aq = a.hprev_b; Bq = a.Whh_b + (n0 - 3072) * 1024; }
      f4 acc[2][4];
      gemm_tile_64x128(Aq, 1024, Bq, 1024, 1024, m0, sm, acc);
      epi_f32(a.gg, 6144, m0, n0, acc, sm, tid);
    }
    round += GRID_BLOCKS; gbar_fast(a.bar, round);

    // ---- Stage C: GRU combine (elementwise, fp32 state, flagged traffic) ----
    for (long i4 = g0; i4 < 512L * 1024 / 4; i4 += gsz) {
      const int b = (int)(i4 >> 8);
      const int c = (int)(i4 & 255) * 4;
      const float* g = a.gg + (long)b * 6144;
      const float nt = a.nont[t * 512 + b];
      f4 gir = ldg_f4(g + c);
      f4 giz = ldg_f4(g + 1024 + c);
      f4 gin = ldg_f4(g + 2048 + c);
      f4 ghr = ldg_f4(g + 3072 + c);
      f4 ghz = ldg_f4(g + 4096 + c);
      f4 ghn = ldg_f4(g + 5120 + c);
      f4 bir = *(const f4*)(a.b_ih + c);
      f4 biz = *(const f4*)(a.b_ih + 1024 + c);
      f4 bin = *(const f4*)(a.b_ih + 2048 + c);
      f4 bhr = *(const f4*)(a.b_hh + c);
      f4 bhz = *(const f4*)(a.b_hh + 1024 + c);
      f4 bhn = *(const f4*)(a.b_hh + 2048 + c);
      f4 hp = ldg_f4(a.h32 + (long)b * 1024 + c);
      union { f4 v; u64 q[2]; } h4;
      union { sh4 s; u64 q; } hb4;
#pragma unroll
      for (int j = 0; j < 4; ++j) {
        float r = sigm_f(gir[j] + bir[j] + ghr[j] + bhr[j]);
        float z = sigm_f(giz[j] + biz[j] + ghz[j] + bhz[j]);
        float n = tanhf(gin[j] + bin[j] + r * (ghn[j] + bhn[j]));
        float hpv = hp[j] * nt;
        float h = (1.f - z) * n + z * hpv;
        h4.v[j] = h; hb4.s[j] = (short)f2b(h);
      }
      stg8(a.h32 + (long)b * 1024 + c, h4.q[0]);
      stg8(a.h32 + (long)b * 1024 + c + 2, h4.q[1]);
      stg8(a.hb + (long)b * 1024 + c, hb4.q);
      *(f4*)(a.out + ((long)t * 512 + b) * 1536 + 512 + c) = h4.v;
    }
    round += GRID_BLOCKS; gbar_fast(a.bar, round);

    // ---- Stage D: p1 = elu(h@Wp1^T+bp1) bf16; q1 split-K fp32 partials ----
    if (bid < 192) {
      f4 acc[2][4];
      const int u = bid & 63;
      const int m0 = (u >> 3) * 64, n0 = (u & 7) * 128;
      if (bid < 64) {
        gemm_tile_64x128(a.hb, 1024, a.Wp1_b + (long)n0 * 1024, 1024, 1024, m0, sm, acc);
        epi_bf16_elu(a.g1, 1024, m0, n0, a.bp1, acc, sm, tid);
      } else if (bid < 128) {
        gemm_tile_64x128(a.hb, 1024, a.Wq1_b + (long)n0 * 2048, 2048, 1024, m0, sm, acc);
        epi_f32(q1a, 1024, m0, n0, acc, sm, tid);
      } else {
        gemm_tile_64x128(a.obs_cur, 1024, a.Wq1_b + (long)n0 * 2048 + 1024, 2048, 1024, m0, sm, acc);
        epi_f32(q1b, 1024, m0, n0, acc, sm, tid);
      }
    }
    round += GRID_BLOCKS; gbar_fast(a.bar, round);

    // ---- Stage E: p2/q2 (16x256, K=1024) + sample + outputs + next xin,
    //      plus hprev/obs prep for step t+1 on otherwise-idle blocks ----
    if (bid < 64) {
      const bool isQ = bid >= 32;
      const int m0 = (bid & 31) * 16;
      const u16* Bq = isQ ? a.Wq2_b : a.Wp2_b;
      const float* bias = isQ ? a.bq2 : a.bp2;
      u16* const sA = (u16*)sm;            // [16][64] swizzled
      u16* const sB = (u16*)(sm + 2048);   // [256][64] swizzled
      const f4 z4 = {0.f, 0.f, 0.f, 0.f};
      f4 acc[4];
#pragma unroll
      for (int j = 0; j < 4; ++j) acc[j] = z4;
      const int am = l & 15, ak = (l >> 4) * 8;
      const int f = tid * 4;
      const int ar = f >> 6, ac = f & 63;
      const int br_ = tid >> 3, bc_ = (tid & 7) * 8;
      f4 va, vb; u64 rA; bh8 rB[8];
      auto fetchE = [&](int k0) {
        if (isQ) {
          long base = (long)(m0 + ar) * 1024 + k0 + ac;
          va = ldg_f4(q1a + base);
          vb = ldg_f4(q1b + base);
        } else {
          rA = ldg8(a.g1 + (long)(m0 + ar) * 1024 + k0 + ac);
        }
#pragma unroll
        for (int i = 0; i < 8; ++i)
          rB[i] = *(const bh8*)(Bq + (long)(i * 32 + br_) * 1024 + k0 + bc_);
      };
      auto putE = [&](int k0) {
        if (isQ) {
          f4 bi = *(const f4*)(a.bq1 + k0 + ac);
          union { u64 u; u16 s[4]; } pk;
#pragma unroll
          for (int j = 0; j < 4; ++j) pk.s[j] = f2b(elu_f(va[j] + vb[j] + bi[j]));
          *(u64*)(sA + SWZ(ar, ac)) = pk.u;
        } else {
          *(u64*)(sA + SWZ(ar, ac)) = rA;
        }
#pragma unroll
        for (int i = 0; i < 8; ++i)
          *(bh8*)(sB + SWZ(i * 32 + br_, bc_)) = rB[i];
      };
      fetchE(0);
      for (int k0 = 0; k0 < 1024; k0 += 64) {
        __syncthreads();
        putE(k0);
        __syncthreads();
        if (k0 + 64 < 1024) fetchE(k0 + 64);  // next loads hidden under MFMAs
#pragma unroll
        for (int kc = 0; kc < 64; kc += 32) {
          bh8 av = *(const bh8*)(sA + SWZ(am, kc + ak));
#pragma unroll
          for (int j = 0; j < 4; ++j) {
            bh8 bv = *(const bh8*)(sB + SWZ(w * 64 + j * 16 + am, kc + ak));
            acc[j] = __builtin_amdgcn_mfma_f32_16x16x32_bf16(av, bv, acc[j], 0, 0, 0);
          }
        }
      }
      __syncthreads();
      float* sq = (float*)sm;  // [16][256], reuses dead staging LDS
      const long ob = (long)t * 512 * 1536;
#pragma unroll
      for (int j = 0; j < 4; ++j)
#pragma unroll
        for (int r = 0; r < 4; ++r) {
          int row = dr + r;
          int col = w * 64 + j * 16 + dc;
          int b = m0 + row;
          float v = acc[j][r] + bias[col];
          float o = (col < 128) ? v : (softplus_f(v) + 0.1f);
          a.out[ob + (long)b * 1536 + (isQ ? 256 : 0) + col] = o;
          if (isQ) sq[row * 256 + col] = o;
        }
      if (isQ && t + 1 < 64) {
        __syncthreads();
        // xin[:, 0:128] = f2b((qm + qs*eps) * nont[t+1]); 4 cols/thread
        for (int it = tid; it < 512; it += THREADS) {
          int row = it >> 5, j0 = (it & 31) * 4, b = m0 + row;
          f4 qm = *(f4*)(sq + row * 256 + j0);
          f4 qs = *(f4*)(sq + row * 256 + 128 + j0);
          f4 ep = *(const f4*)(a.noise + ((long)t * 512 + b) * 128 + j0);
          float ntn = a.nont[(t + 1) * 512 + b];
          union { sh4 s; u64 q; } pk;
#pragma unroll
          for (int j = 0; j < 4; ++j)
            pk.s[j] = (short)f2b((qm[j] + qs[j] * ep[j]) * ntn);
          stg8(a.xin + (long)b * 192 + j0, pk.q);
        }
        // xin[:, 128:144] = actions[t+1]
        if (tid < 64) {
          int row = tid >> 2, ja = (tid & 3) * 4, b = m0 + row;
          f4 av = *(const f4*)(a.actions + ((long)(t + 1) * 512 + b) * 16 + ja);
          union { sh4 s; u64 q; } pk;
#pragma unroll
          for (int j = 0; j < 4; ++j) pk.s[j] = (short)f2b(av[j]);
          stg8(a.xin + (long)b * 192 + 128 + ja, pk.q);
        }
      }
    } else if (bid < 192) {
      // hprev_b for step t+1 = h(t) * nont[t+1]
      if (t + 1 < 64) {
        const int base = (bid - 64) * 4096;
        for (int i = tid; i < 1024; i += THREADS) {
          int idx = base + i * 4, b = idx >> 10;
          float ntn = a.nont[(t + 1) * 512 + b];
          f4 v = ldg_f4(a.h32 + idx);
          union { sh4 s; u64 q; } o;
#pragma unroll
          for (int j = 0; j < 4; ++j) o.s[j] = (short)f2b(v[j] * ntn);
          stg8(a.hprev_b + idx, o.q);
        }
      }
    } else if (bid < 320) {
      // obs_cur for step t+1
      if (t + 1 < 64) {
        const int base = (bid - 192) * 4096;
        const float* op = a.obs + (long)(t + 1) * 512 * 1024;
        for (int i = tid; i < 1024; i += THREADS) {
          int idx = base + i * 4;
          f4 v = *(const f4*)(op + idx);
          union { sh4 s; u64 q; } o;
#pragma unroll
          for (int j = 0; j < 4; ++j) o.s[j] = (short)f2b(v[j]);
          stg8(a.obs_cur + idx, o.q);
        }
      }
    }
    round += GRID_BLOCKS; gbar_fast(a.bar, round);
  }
}

extern "C" void kernel_launch(void* const* d_in, const int* in_sizes, int n_in,
                              void* d_out, int out_size, void* d_ws, size_t ws_size,
                              hipStream_t stream) {
  RArgs a;
  a.actions    = (const float*)d_in[0];
  a.nont       = (const float*)d_in[1];
  a.obs        = (const float*)d_in[2];
  a.noise      = (const float*)d_in[3];
  a.init_stoc  = (const float*)d_in[4];
  a.init_deter = (const float*)d_in[5];
  a.W_in = (const float*)d_in[6];  a.b_in = (const float*)d_in[7];
  a.W_ih = (const float*)d_in[8];  a.W_hh = (const float*)d_in[9];
  a.b_ih = (const float*)d_in[10]; a.b_hh = (const float*)d_in[11];
  a.Wp1 = (const float*)d_in[12];  a.bp1 = (const float*)d_in[13];
  a.Wp2 = (const float*)d_in[14];  a.bp2 = (const float*)d_in[15];
  a.Wq1 = (const float*)d_in[16];  a.bq1 = (const float*)d_in[17];
  a.Wq2 = (const float*)d_in[18];  a.bq2 = (const float*)d_in[19];
  a.out = (float*)d_out;

  char* p = (char*)d_ws;
  auto alloc = [&](size_t bytes) { char* r = p; p += (bytes + 255) & ~(size_t)255; return r; };
  a.bar     = (int*)alloc(256);
  a.Wi_b    = (u16*)alloc(1024 * 192 * 2);
  a.Wih_b   = (u16*)alloc((size_t)3072 * 1024 * 2);
  a.Whh_b   = (u16*)alloc((size_t)3072 * 1024 * 2);
  a.Wp1_b   = (u16*)alloc((size_t)1024 * 1024 * 2);
  a.Wp2_b   = (u16*)alloc((size_t)256 * 1024 * 2);
  a.Wq1_b   = (u16*)alloc((size_t)1024 * 2048 * 2);
  a.Wq2_b   = (u16*)alloc((size_t)256 * 1024 * 2);
  a.xin     = (u16*)alloc((size_t)512 * 192 * 2);
  a.x_b     = (u16*)alloc((size_t)512 * 1024 * 2);
  a.hprev_b = (u16*)alloc((size_t)512 * 1024 * 2);
  a.hb      = (u16*)alloc((size_t)512 * 1024 * 2);
  a.obs_cur = (u16*)alloc((size_t)512 * 1024 * 2);
  a.g1      = (u16*)alloc((size_t)512 * 1024 * 2);
  a.h32     = (float*)alloc((size_t)512 * 1024 * 4);
  a.gg      = (float*)alloc((size_t)512 * 6144 * 4);

  hipMemsetAsync(a.bar, 0, 256, stream);
  rssm_kernel<<<dim3(GRID_BLOCKS), dim3(THREADS), 0, stream>>>(a);
}

// Round 3
// 6283.542 us; speedup vs baseline: 6.7912x; 1.7163x over previous
//
#include <hip/hip_runtime.h>

typedef unsigned short u16;
typedef __attribute__((ext_vector_type(8))) short bh8;
typedef __attribute__((ext_vector_type(4))) short sh4;
typedef __attribute__((ext_vector_type(4))) float f4;
typedef unsigned long long u64;

#define GRID_BLOCKS 512
#define THREADS 256
// XOR swizzle at 8-element (16B) granularity within a 64-u16 row.
#define SWZ(r, c) ((((r) * 64 + (c))) ^ ((((r) & 7)) << 3))
#define SFLD 132   // f32 epilogue LDS row stride (16B-aligned, bank-spread)

__device__ __forceinline__ u16 f2b(float f) {
  unsigned u = __float_as_uint(f);
  return (u16)((u + 0x7FFFu + ((u >> 16) & 1u)) >> 16);
}
__device__ __forceinline__ float elu_f(float x) { return x > 0.f ? x : __expf(x) - 1.f; }
__device__ __forceinline__ float sigm_f(float x) { return 1.f / (1.f + __expf(-x)); }
__device__ __forceinline__ float softplus_f(float x) { return x > 20.f ? x : log1pf(__expf(x)); }

// ---- coherent (XCD-L2-bypassing) accessors for cross-block activations ----
__device__ __forceinline__ u64 ldg8(const void* p) {
  return __hip_atomic_load((const u64*)p, __ATOMIC_RELAXED, __HIP_MEMORY_SCOPE_AGENT);
}
__device__ __forceinline__ void stg8(void* p, u64 v) {
  __hip_atomic_store((u64*)p, v, __ATOMIC_RELAXED, __HIP_MEMORY_SCOPE_AGENT);
}
__device__ __forceinline__ f4 ldg_f4(const float* p) {
  union { u64 q[2]; f4 v; } u;
  u.q[0] = ldg8(p); u.q[1] = ldg8(p + 2);
  return u.v;
}
__device__ __forceinline__ bh8 ldg_bh8(const u16* p) {
  union { u64 q[2]; bh8 v; } u;
  u.q[0] = ldg8(p); u.q[1] = ldg8(p + 4);
  return u.v;
}

// Full-fence barrier: ONLY for init (plain-stored weights pushed to L3 once).
__device__ __forceinline__ void gbar_full(int* cnt, int target) {
  __syncthreads();
  if (threadIdx.x == 0) {
    __threadfence();
    __hip_atomic_fetch_add(cnt, 1, __ATOMIC_RELEASE, __HIP_MEMORY_SCOPE_AGENT);
    while (__hip_atomic_load(cnt, __ATOMIC_ACQUIRE, __HIP_MEMORY_SCOPE_AGENT) < target)
      __builtin_amdgcn_s_sleep(8);
    __threadfence();
  }
  __syncthreads();
}

// Fence-free hierarchical barrier: 16 groups x 32 blocks. Members add/poll
// a group-local line; the last arriver of each group touches the global
// line; leaders release members via per-group 'go' epochs. All cross-stage
// data moves via sc-flagged (agent-coherent) ops; __syncthreads drains
// vmcnt so flagged stores are at the coherence point before the add.
__device__ __forceinline__ void gbar_fast(int* bar, int round, int bid) {
  __syncthreads();
  if (threadIdx.x == 0) {
    const int g = bid >> 5;                 // 16 groups of 32 consecutive
    int* arr  = bar + g * 32;               // group arrival counters
    int* glob = bar + 512;                  // global group counter
    int* go   = bar + 544 + g * 32;         // per-group release epoch
    int old = __hip_atomic_fetch_add(arr, 1, __ATOMIC_RELAXED, __HIP_MEMORY_SCOPE_AGENT);
    if (old == round * 32 - 1) {            // last arriver of my group
      __hip_atomic_fetch_add(glob, 1, __ATOMIC_RELAXED, __HIP_MEMORY_SCOPE_AGENT);
      while (__hip_atomic_load(glob, __ATOMIC_RELAXED, __HIP_MEMORY_SCOPE_AGENT) < round * 16)
        __builtin_amdgcn_s_sleep(2);
      __hip_atomic_store(go, round, __ATOMIC_RELAXED, __HIP_MEMORY_SCOPE_AGENT);
    } else {
      while (__hip_atomic_load(go, __ATOMIC_RELAXED, __HIP_MEMORY_SCOPE_AGENT) < round)
        __builtin_amdgcn_s_sleep(2);
    }
  }
  __syncthreads();
}

struct RArgs {
  const float* actions; const float* nont; const float* obs; const float* noise;
  const float* init_stoc; const float* init_deter;
  const float* W_in; const float* b_in; const float* W_ih; const float* W_hh;
  const float* b_ih; const float* b_hh;
  const float* Wp1; const float* bp1; const float* Wp2; const float* bp2;
  const float* Wq1; const float* bq1; const float* Wq2; const float* bq2;
  float* out;
  u16 *Wi_b, *Wih_b, *Whh_b, *Wp1_b, *Wp2_b, *Wq1_b, *Wq2_b;
  u16 *xin, *x_b, *hprev_b, *hb, *obs_cur, *g1;
  float *h32, *gg;
  int* bar;
};

// C[64x128] = A[64xK] * B^T[128xK], bf16 in, fp32 acc.
// A = activations (flagged loads, L3 latency) -> DEPTH-2 register prefetch.
// B = weights (plain loads, L2-resident)      -> depth-1 suffices.
// Double-buffered swizzled LDS, 1 sync per 64-wide K slab.
__device__ __forceinline__ void gemm_tile_64x128(
    const u16* A, long lda, const u16* Bw, long ldb, int K, int m0,
    char* sm, f4 acc[2][4])
{
  u16* const sA0 = (u16*)sm;              // 8192 B each
  u16* const sA1 = (u16*)(sm + 8192);
  u16* const sB0 = (u16*)(sm + 16384);    // 16384 B each
  u16* const sB1 = (u16*)(sm + 32768);
  const int tid = threadIdx.x;
  const int l = tid & 63, w = tid >> 6;
  const int wrow = (w & 1) * 32, wcol = (w >> 1) * 64;
  const int am = l & 15, ak = (l >> 4) * 8;
  const int arow = tid >> 2, acol = (tid & 3) * 16;
  const int brow = tid >> 1, bcol = (tid & 1) * 32;
  const f4 z4 = {0.f, 0.f, 0.f, 0.f};
#pragma unroll
  for (int i = 0; i < 2; ++i)
#pragma unroll
    for (int j = 0; j < 4; ++j) acc[i][j] = z4;

  const u16* asrc = A + (long)(m0 + arow) * lda + acol;
  const u16* bsrc = Bw + (long)brow * ldb + bcol;

  // A prefetch sets: slab j lives in set (j&1). Named sets = static indexing.
  bh8 a0_0, a1_0, a0_1, a1_1;
  bh8 rb0, rb1, rb2, rb3;                 // B prefetch (depth-1)
  auto fetchA0 = [&](int k0) { a0_0 = ldg_bh8(asrc + k0); a1_0 = ldg_bh8(asrc + k0 + 8); };
  auto fetchA1 = [&](int k0) { a0_1 = ldg_bh8(asrc + k0); a1_1 = ldg_bh8(asrc + k0 + 8); };
  auto fetchB = [&](int k0) {
    rb0 = *(const bh8*)(bsrc + k0);
    rb1 = *(const bh8*)(bsrc + k0 + 8);
    rb2 = *(const bh8*)(bsrc + k0 + 16);
    rb3 = *(const bh8*)(bsrc + k0 + 24);
  };
  auto putA = [&](u16* dA, int s) {
    *(bh8*)(dA + SWZ(arow, acol))     = s ? a0_1 : a0_0;
    *(bh8*)(dA + SWZ(arow, acol + 8)) = s ? a1_1 : a1_0;
  };
  auto putB = [&](u16* dB) {
    *(bh8*)(dB + SWZ(brow, bcol))      = rb0;
    *(bh8*)(dB + SWZ(brow, bcol + 8))  = rb1;
    *(bh8*)(dB + SWZ(brow, bcol + 16)) = rb2;
    *(bh8*)(dB + SWZ(brow, bcol + 24)) = rb3;
  };

  const int nIter = K >> 6;
  fetchA0(0); fetchB(0);
  if (nIter > 1) fetchA1(64);
  putA(sA0, 0); putB(sB0);
  for (int i = 0; i < nIter; ++i) {
    __syncthreads();                       // buf (i&1) ready; prev reads done
    if (i + 2 < nIter) {                   // fetch A slab i+2 into set (i&1)
      if (i & 1) fetchA1((i + 2) << 6); else fetchA0((i + 2) << 6);
    }
    if (i + 1 < nIter) fetchB((i + 1) << 6);
    const u16* cA = (i & 1) ? sA1 : sA0;
    const u16* cB = (i & 1) ? sB1 : sB0;
#pragma unroll
    for (int kc = 0; kc < 64; kc += 32) {
      bh8 a0 = *(const bh8*)(cA + SWZ(wrow + am, kc + ak));
      bh8 a1 = *(const bh8*)(cA + SWZ(wrow + 16 + am, kc + ak));
#pragma unroll
      for (int j = 0; j < 4; ++j) {
        bh8 bv = *(const bh8*)(cB + SWZ(wcol + j * 16 + am, kc + ak));
        acc[0][j] = __builtin_amdgcn_mfma_f32_16x16x32_bf16(a0, bv, acc[0][j], 0, 0, 0);
        acc[1][j] = __builtin_amdgcn_mfma_f32_16x16x32_bf16(a1, bv, acc[1][j], 0, 0, 0);
      }
    }
    if (i + 1 < nIter) {                   // stage slab i+1 into buf (i+1)&1
      u16* dA = (i & 1) ? sA0 : sA1;
      u16* dB = (i & 1) ? sB0 : sB1;
      putA(dA, (i + 1) & 1);
      putB(dB);
    }
  }
  __syncthreads();
}

// ---- epilogues: fragment -> LDS f32 [64][SFLD] -> linear coalesced flagged
// stores (keeps cross-block stores 8B-granular and wave-contiguous) ----
__device__ __forceinline__ void frag_to_lds(float* sf, const f4 acc[2][4], int tid) {
  const int l = tid & 63, w = tid >> 6;
  const int dr = (l >> 4) * 4, dc = l & 15;
  const int wrow = (w & 1) * 32, wcol = (w >> 1) * 64;
#pragma unroll
  for (int i = 0; i < 2; ++i)
#pragma unroll
    for (int j = 0; j < 4; ++j)
#pragma unroll
      for (int r = 0; r < 4; ++r)
        sf[(wrow + i * 16 + dr + r) * SFLD + wcol + j * 16 + dc] = acc[i][j][r];
}

__device__ __forceinline__ void epi_bf16_elu(u16* dst, long ldd, int m0, long n0,
                                             const float* bias, const f4 acc[2][4],
                                             char* sm, int tid) {
  float* sf = (float*)sm;
  frag_to_lds(sf, acc, tid);
  __syncthreads();
  for (int it = tid; it < 2048; it += THREADS) {
    int row = it >> 5, c4 = (it & 31) * 4;
    f4 v = *(f4*)(sf + row * SFLD + c4);
    f4 b = *(const f4*)(bias + n0 + c4);
    union { sh4 s; u64 q; } pk;
#pragma unroll
    for (int j = 0; j < 4; ++j) pk.s[j] = (short)f2b(elu_f(v[j] + b[j]));
    stg8(dst + (long)(m0 + row) * ldd + n0 + c4, pk.q);
  }
}

__device__ __forceinline__ void epi_f32(float* dst, long ldd, int m0, long n0,
                                        const f4 acc[2][4], char* sm, int tid) {
  float* sf = (float*)sm;
  frag_to_lds(sf, acc, tid);
  __syncthreads();
  for (int it = tid; it < 2048; it += THREADS) {
    int row = it >> 5, c4 = (it & 31) * 4;
    union { f4 v; u64 q[2]; } u;
    u.v = *(f4*)(sf + row * SFLD + c4);
    float* d = dst + (long)(m0 + row) * ldd + n0 + c4;
    stg8(d, u.q[0]); stg8(d + 2, u.q[1]);
  }
}

__global__ __launch_bounds__(THREADS, 2) void rssm_kernel(RArgs a) {
  __shared__ __align__(16) char sm[69632];
  const int tid = threadIdx.x;
  const int bid = blockIdx.x;
  const long gsz = (long)GRID_BLOCKS * THREADS;
  const long g0 = (long)bid * THREADS + tid;
  const int l = tid & 63, w = tid >> 6;
  const int dr = (l >> 4) * 4, dc = l & 15;
  float* const q1a = a.gg;
  float* const q1b = a.gg + (long)512 * 1024;
  int rnd = 0;

  // ---- init / weight conversion (every call: ws is re-poisoned) ----
  for (long i = g0; i < 3072L * 1024 / 4; i += gsz) {
    f4 v1 = *(const f4*)(a.W_ih + i * 4);
    f4 v2 = *(const f4*)(a.W_hh + i * 4);
    sh4 o1 = {(short)f2b(v1[0]), (short)f2b(v1[1]), (short)f2b(v1[2]), (short)f2b(v1[3])};
    sh4 o2 = {(short)f2b(v2[0]), (short)f2b(v2[1]), (short)f2b(v2[2]), (short)f2b(v2[3])};
    *(sh4*)(a.Wih_b + i * 4) = o1;
    *(sh4*)(a.Whh_b + i * 4) = o2;
  }
  for (long i = g0; i < 1024L * 2048 / 4; i += gsz) {
    f4 v = *(const f4*)(a.Wq1 + i * 4);
    sh4 o = {(short)f2b(v[0]), (short)f2b(v[1]), (short)f2b(v[2]), (short)f2b(v[3])};
    *(sh4*)(a.Wq1_b + i * 4) = o;
  }
  for (long i = g0; i < 1024L * 1024 / 4; i += gsz) {
    f4 v = *(const f4*)(a.Wp1 + i * 4);
    sh4 o = {(short)f2b(v[0]), (short)f2b(v[1]), (short)f2b(v[2]), (short)f2b(v[3])};
    *(sh4*)(a.Wp1_b + i * 4) = o;
  }
  for (long i = g0; i < 256L * 1024 / 4; i += gsz) {
    f4 v = *(const f4*)(a.Wp2 + i * 4);
    f4 u = *(const f4*)(a.Wq2 + i * 4);
    sh4 o1 = {(short)f2b(v[0]), (short)f2b(v[1]), (short)f2b(v[2]), (short)f2b(v[3])};
    sh4 o2 = {(short)f2b(u[0]), (short)f2b(u[1]), (short)f2b(u[2]), (short)f2b(u[3])};
    *(sh4*)(a.Wp2_b + i * 4) = o1;
    *(sh4*)(a.Wq2_b + i * 4) = o2;
  }
  for (long i = g0; i < 1024 * 192; i += gsz) {
    long n = i / 192, k = i - n * 192;
    a.Wi_b[i] = (k < 144) ? f2b(a.W_in[n * 144 + k]) : (u16)0;
  }
  for (long i = g0; i < 512L * 1024 / 4; i += gsz) {
    f4 v = *(const f4*)(a.init_deter + i * 4);
    *(f4*)(a.h32 + i * 4) = v;
    float nt0 = a.nont[(i * 4) >> 10];
    sh4 o = {(short)f2b(v[0] * nt0), (short)f2b(v[1] * nt0),
             (short)f2b(v[2] * nt0), (short)f2b(v[3] * nt0)};
    *(sh4*)(a.hprev_b + i * 4) = o;
  }
  for (long i = g0; i < 512L * 1024 / 4; i += gsz) {
    f4 v = *(const f4*)(a.obs + i * 4);
    sh4 o = {(short)f2b(v[0]), (short)f2b(v[1]), (short)f2b(v[2]), (short)f2b(v[3])};
    *(sh4*)(a.obs_cur + i * 4) = o;
  }
  for (long i = g0; i < 512 * 192; i += gsz) {
    long b = i / 192, k = i - b * 192;
    float v = 0.f;
    if (k < 128) v = a.init_stoc[b * 128 + k] * a.nont[b];
    else if (k < 144) v = a.actions[b * 16 + (k - 128)];
    a.xin[i] = f2b(v);
  }
  gbar_full(a.bar + 1088, GRID_BLOCKS);

  for (int t = 0; t < 64; ++t) {
    // ---- Stage A: x = elu([stoc*nt ; a] @ W_in^T + b_in) ----
    if (bid < 64) {
      const int m0 = (bid >> 3) * 64, n0 = (bid & 7) * 128;
      f4 acc[2][4];
      gemm_tile_64x128(a.xin, 192, a.Wi_b + (long)n0 * 192, 192, 192, m0, sm, acc);
      epi_bf16_elu(a.x_b, 1024, m0, n0, a.b_in, acc, sm, tid);
    }
    ++rnd; gbar_fast(a.bar, rnd, bid);

    // ---- Stage B: gi = x @ W_ih^T ; gh = (h_prev*nt) @ W_hh^T  (raw, fp32) ----
    if (bid < 384) {
      const int tm = bid / 48, tn = bid - tm * 48;
      const int m0 = tm * 64; const long n0 = (long)tn * 128;
      const u16* Aq; const u16* Bq;
      if (n0 < 3072) { Aq = a.x_b;     Bq = a.Wih_b + n0 * 1024; }
      else           { Aq = a.hprev_b; Bq = a.Whh_b + (n0 - 3072) * 1024; }
      f4 acc[2][4];
      gemm_tile_64x128(Aq, 1024, Bq, 1024, 1024, m0, sm, acc);
      epi_f32(a.gg, 6144, m0, n0, acc, sm, tid);
    }
    ++rnd; gbar_fast(a.bar, rnd, bid);

    // ---- Stage C: GRU combine (elementwise, fp32 state, flagged traffic) ----
    for (long i4 = g0; i4 < 512L * 1024 / 4; i4 += gsz) {
      const int b = (int)(i4 >> 8);
      const int c = (int)(i4 & 255) * 4;
      const float* g = a.gg + (long)b * 6144;
      const float nt = a.nont[t * 512 + b];
      f4 gir = ldg_f4(g + c);
      f4 giz = ldg_f4(g + 1024 + c);
      f4 gin = ldg_f4(g + 2048 + c);
      f4 ghr = ldg_f4(g + 3072 + c);
      f4 ghz = ldg_f4(g + 4096 + c);
      f4 ghn = ldg_f4(g + 5120 + c);
      f4 bir = *(const f4*)(a.b_ih + c);
      f4 biz = *(const f4*)(a.b_ih + 1024 + c);
      f4 bin = *(const f4*)(a.b_ih + 2048 + c);
      f4 bhr = *(const f4*)(a.b_hh + c);
      f4 bhz = *(const f4*)(a.b_hh + 1024 + c);
      f4 bhn = *(const f4*)(a.b_hh + 2048 + c);
      f4 hp = ldg_f4(a.h32 + (long)b * 1024 + c);
      union { f4 v; u64 q[2]; } h4;
      union { sh4 s; u64 q; } hb4;
#pragma unroll
      for (int j = 0; j < 4; ++j) {
        float r = sigm_f(gir[j] + bir[j] + ghr[j] + bhr[j]);
        float z = sigm_f(giz[j] + biz[j] + ghz[j] + bhz[j]);
        float n = tanhf(gin[j] + bin[j] + r * (ghn[j] + bhn[j]));
        float hpv = hp[j] * nt;
        float h = (1.f - z) * n + z * hpv;
        h4.v[j] = h; hb4.s[j] = (short)f2b(h);
      }
      stg8(a.h32 + (long)b * 1024 + c, h4.q[0]);
      stg8(a.h32 + (long)b * 1024 + c + 2, h4.q[1]);
      stg8(a.hb + (long)b * 1024 + c, hb4.q);
      *(f4*)(a.out + ((long)t * 512 + b) * 1536 + 512 + c) = h4.v;
    }
    ++rnd; gbar_fast(a.bar, rnd, bid);

    // ---- Stage D: p1 = elu(h@Wp1^T+bp1) bf16; q1 split-K fp32 partials ----
    if (bid < 192) {
      f4 acc[2][4];
      const int u = bid & 63;
      const int m0 = (u >> 3) * 64, n0 = (u & 7) * 128;
      if (bid < 64) {
        gemm_tile_64x128(a.hb, 1024, a.Wp1_b + (long)n0 * 1024, 1024, 1024, m0, sm, acc);
        epi_bf16_elu(a.g1, 1024, m0, n0, a.bp1, acc, sm, tid);
      } else if (bid < 128) {
        gemm_tile_64x128(a.hb, 1024, a.Wq1_b + (long)n0 * 2048, 2048, 1024, m0, sm, acc);
        epi_f32(q1a, 1024, m0, n0, acc, sm, tid);
      } else {
        gemm_tile_64x128(a.obs_cur, 1024, a.Wq1_b + (long)n0 * 2048 + 1024, 2048, 1024, m0, sm, acc);
        epi_f32(q1b, 1024, m0, n0, acc, sm, tid);
      }
    }
    ++rnd; gbar_fast(a.bar, rnd, bid);

    // ---- Stage E: p2/q2 (16x256, K=1024), 1-sync/iter dbuf + depth-2 A ----
    if (bid < 64) {
      const bool isQ = bid >= 32;
      const int m0 = (bid & 31) * 16;
      const u16* Bq = isQ ? a.Wq2_b : a.Wp2_b;
      const float* bias = isQ ? a.bq2 : a.bp2;
      u16* const sA0 = (u16*)sm;             // [16][64] swizzled, 2KB each
      u16* const sA1 = (u16*)(sm + 2048);
      u16* const sB0 = (u16*)(sm + 4096);    // [256][64] swizzled, 32KB each
      u16* const sB1 = (u16*)(sm + 36864);
      const f4 z4 = {0.f, 0.f, 0.f, 0.f};
      f4 acc[4];
#pragma unroll
      for (int j = 0; j < 4; ++j) acc[j] = z4;
      const int am = l & 15, ak = (l >> 4) * 8;
      const int f = tid * 4;
      const int ar = f >> 6, ac = f & 63;
      const int br_ = tid >> 3, bc_ = (tid & 7) * 8;
      // A: depth-2 prefetch (flagged L3); B: depth-1 (plain, L2-resident)
      f4 va_0, vb_0, va_1, vb_1; u64 rA_0, rA_1; bh8 rB[8];
      auto fetchA0 = [&](int k0) {
        if (isQ) { long b_ = (long)(m0 + ar) * 1024 + k0 + ac;
                   va_0 = ldg_f4(q1a + b_); vb_0 = ldg_f4(q1b + b_); }
        else rA_0 = ldg8(a.g1 + (long)(m0 + ar) * 1024 + k0 + ac);
      };
      auto fetchA1 = [&](int k0) {
        if (isQ) { long b_ = (long)(m0 + ar) * 1024 + k0 + ac;
                   va_1 = ldg_f4(q1a + b_); vb_1 = ldg_f4(q1b + b_); }
        else rA_1 = ldg8(a.g1 + (long)(m0 + ar) * 1024 + k0 + ac);
      };
      auto fetchB = [&](int k0) {
#pragma unroll
        for (int i = 0; i < 8; ++i)
          rB[i] = *(const bh8*)(Bq + (long)(i * 32 + br_) * 1024 + k0 + bc_);
      };
      auto putA = [&](u16* dA, int k0, int s) {
        if (isQ) {
          f4 bi = *(const f4*)(a.bq1 + k0 + ac);
          f4 va = s ? va_1 : va_0, vb = s ? vb_1 : vb_0;
          union { u64 u; u16 sh[4]; } pk;
#pragma unroll
          for (int j = 0; j < 4; ++j) pk.sh[j] = f2b(elu_f(va[j] + vb[j] + bi[j]));
          *(u64*)(dA + SWZ(ar, ac)) = pk.u;
        } else {
          *(u64*)(dA + SWZ(ar, ac)) = s ? rA_1 : rA_0;
        }
      };
      auto putB = [&](u16* dB) {
#pragma unroll
        for (int i = 0; i < 8; ++i)
          *(bh8*)(dB + SWZ(i * 32 + br_, bc_)) = rB[i];
      };
      fetchA0(0); fetchB(0);
      fetchA1(64);
      putA(sA0, 0, 0); putB(sB0);
      for (int i = 0; i < 16; ++i) {
        __syncthreads();
        if (i + 2 < 16) { if (i & 1) fetchA1((i + 2) << 6); else fetchA0((i + 2) << 6); }
        if (i + 1 < 16) fetchB((i + 1) << 6);
        const u16* cA = (i & 1) ? sA1 : sA0;
        const u16* cB = (i & 1) ? sB1 : sB0;
#pragma unroll
        for (int kc = 0; kc < 64; kc += 32) {
          bh8 av = *(const bh8*)(cA + SWZ(am, kc + ak));
#pragma unroll
          for (int j = 0; j < 4; ++j) {
            bh8 bv = *(const bh8*)(cB + SWZ(w * 64 + j * 16 + am, kc + ak));
            acc[j] = __builtin_amdgcn_mfma_f32_16x16x32_bf16(av, bv, acc[j], 0, 0, 0);
          }
        }
        if (i + 1 < 16) {
          u16* dA = (i & 1) ? sA0 : sA1;
          u16* dB = (i & 1) ? sB0 : sB1;
          putA(dA, (i + 1) << 6, (i + 1) & 1);
          putB(dB);
        }
      }
      __syncthreads();
      float* sq = (float*)sm;  // [16][256], reuses dead staging LDS
      const long ob = (long)t * 512 * 1536;
#pragma unroll
      for (int j = 0; j < 4; ++j)
#pragma unroll
        for (int r = 0; r < 4; ++r) {
          int row = dr + r;
          int col = w * 64 + j * 16 + dc;
          int b = m0 + row;
          float v = acc[j][r] + bias[col];
          float o = (col < 128) ? v : (softplus_f(v) + 0.1f);
          a.out[ob + (long)b * 1536 + (isQ ? 256 : 0) + col] = o;
          if (isQ) sq[row * 256 + col] = o;
        }
      if (isQ && t + 1 < 64) {
        __syncthreads();
        for (int it = tid; it < 512; it += THREADS) {
          int row = it >> 5, j0 = (it & 31) * 4, b = m0 + row;
          f4 qm = *(f4*)(sq + row * 256 + j0);
          f4 qs = *(f4*)(sq + row * 256 + 128 + j0);
          f4 ep = *(const f4*)(a.noise + ((long)t * 512 + b) * 128 + j0);
          float ntn = a.nont[(t + 1) * 512 + b];
          union { sh4 s; u64 q; } pk;
#pragma unroll
          for (int j = 0; j < 4; ++j)
            pk.s[j] = (short)f2b((qm[j] + qs[j] * ep[j]) * ntn);
          stg8(a.xin + (long)b * 192 + j0, pk.q);
        }
        if (tid < 64) {
          int row = tid >> 2, ja = (tid & 3) * 4, b = m0 + row;
          f4 av = *(const f4*)(a.actions + ((long)(t + 1) * 512 + b) * 16 + ja);
          union { sh4 s; u64 q; } pk;
#pragma unroll
          for (int j = 0; j < 4; ++j) pk.s[j] = (short)f2b(av[j]);
          stg8(a.xin + (long)b * 192 + 128 + ja, pk.q);
        }
      }
    } else if (bid < 192) {
      // hprev_b for step t+1 = h(t) * nont[t+1]
      if (t + 1 < 64) {
        const int base = (bid - 64) * 4096;
        for (int i = tid; i < 1024; i += THREADS) {
          int idx = base + i * 4, b = idx >> 10;
          float ntn = a.nont[(t + 1) * 512 + b];
          f4 v = ldg_f4(a.h32 + idx);
          union { sh4 s; u64 q; } o;
#pragma unroll
          for (int j = 0; j < 4; ++j) o.s[j] = (short)f2b(v[j] * ntn);
          stg8(a.hprev_b + idx, o.q);
        }
      }
    } else if (bid < 320) {
      // obs_cur for step t+1
      if (t + 1 < 64) {
        const int base = (bid - 192) * 4096;
        const float* op = a.obs + (long)(t + 1) * 512 * 1024;
        for (int i = tid; i < 1024; i += THREADS) {
          int idx = base + i * 4;
          f4 v = *(const f4*)(op + idx);
          union { sh4 s; u64 q; } o;
#pragma unroll
          for (int j = 0; j < 4; ++j) o.s[j] = (short)f2b(v[j]);
          stg8(a.obs_cur + idx, o.q);
        }
      }
    }
    ++rnd; gbar_fast(a.bar, rnd, bid);
  }
}

extern "C" void kernel_launch(void* const* d_in, const int* in_sizes, int n_in,
                              void* d_out, int out_size, void* d_ws, size_t ws_size,
                              hipStream_t stream) {
  RArgs a;
  a.actions    = (const float*)d_in[0];
  a.nont       = (const float*)d_in[1];
  a.obs        = (const float*)d_in[2];
  a.noise      = (const float*)d_in[3];
  a.init_stoc  = (const float*)d_in[4];
  a.init_deter = (const float*)d_in[5];
  a.W_in = (const float*)d_in[6];  a.b_in = (const float*)d_in[7];
  a.W_ih = (const float*)d_in[8];  a.W_hh = (const float*)d_in[9];
  a.b_ih = (const float*)d_in[10]; a.b_hh = (const float*)d_in[11];
  a.Wp1 = (const float*)d_in[12];  a.bp1 = (const float*)d_in[13];
  a.Wp2 = (const float*)d_in[14];  a.bp2 = (const float*)d_in[15];
  a.Wq1 = (const float*)d_in[16];  a.bq1 = (const float*)d_in[17];
  a.Wq2 = (const float*)d_in[18];  a.bq2 = (const float*)d_in[19];
  a.out = (float*)d_out;

  char* p = (char*)d_ws;
  auto alloc = [&](size_t bytes) { char* r = p; p += (bytes + 255) & ~(size_t)255; return r; };
  a.bar     = (int*)alloc(8192);
  a.Wi_b    = (u16*)alloc(1024 * 192 * 2);
  a.Wih_b   = (u16*)alloc((size_t)3072 * 1024 * 2);
  a.Whh_b   = (u16*)alloc((size_t)3072 * 1024 * 2);
  a.Wp1_b   = (u16*)alloc((size_t)1024 * 1024 * 2);
  a.Wp2_b   = (u16*)alloc((size_t)256 * 1024 * 2);
  a.Wq1_b   = (u16*)alloc((size_t)1024 * 2048 * 2);
  a.Wq2_b   = (u16*)alloc((size_t)256 * 1024 * 2);
  a.xin     = (u16*)alloc((size_t)512 * 192 * 2);
  a.x_b     = (u16*)alloc((size_t)512 * 1024 * 2);
  a.hprev_b = (u16*)alloc((size_t)512 * 1024 * 2);
  a.hb      = (u16*)alloc((size_t)512 * 1024 * 2);
  a.obs_cur = (u16*)alloc((size_t)512 * 1024 * 2);
  a.g1      = (u16*)alloc((size_t)512 * 1024 * 2);
  a.h32     = (float*)alloc((size_t)512 * 1024 * 4);
  a.gg      = (float*)alloc((size_t)512 * 6144 * 4);

  hipMemsetAsync(a.bar, 0, 8192, stream);
  rssm_kernel<<<dim3(GRID_BLOCKS), dim3(THREADS), 0, stream>>>(a);
}